// Round 2
// baseline (888.744 us; speedup 1.0000x reference)
//
#include <hip/hip_runtime.h>
#include <hip/hip_bf16.h>

// Problem constants: B=2, S=2048, HID=2048, H=16, HD=128, HD2=64, LAT=256
#define BB 2
#define SS 2048
#define HID 2048
#define NH 16
#define HD 128
#define HD2 64
#define LAT 256
#define BS (BB*SS)          // 4096 rows
#define SCALE 0.088388347648318447f   // 1/sqrt(128)

typedef __bf16 bf16x8 __attribute__((ext_vector_type(8)));
typedef float f32x4 __attribute__((ext_vector_type(4)));

__device__ __forceinline__ bf16x8 ld_frag(const __hip_bfloat16* p) {
    uint4 u = *reinterpret_cast<const uint4*>(p);
    return __builtin_bit_cast(bf16x8, u);
}

// load 8 contiguous elements -> 8 bf16 in a local array
__device__ __forceinline__ void load8(const float* p, __hip_bfloat16* dst) {
    float4 a = *reinterpret_cast<const float4*>(p);
    float4 b = *reinterpret_cast<const float4*>(p + 4);
    dst[0] = __float2bfloat16(a.x); dst[1] = __float2bfloat16(a.y);
    dst[2] = __float2bfloat16(a.z); dst[3] = __float2bfloat16(a.w);
    dst[4] = __float2bfloat16(b.x); dst[5] = __float2bfloat16(b.y);
    dst[6] = __float2bfloat16(b.z); dst[7] = __float2bfloat16(b.w);
}
__device__ __forceinline__ void load8(const __hip_bfloat16* p, __hip_bfloat16* dst) {
    *reinterpret_cast<uint4*>(dst) = *reinterpret_cast<const uint4*>(p);
}
__device__ __forceinline__ void store_c(__hip_bfloat16* C, size_t idx, float v) {
    C[idx] = __float2bfloat16(v);
}
__device__ __forceinline__ void store_c(float* C, size_t idx, float v) {
    C[idx] = v;
}

// ---------------------------------------------------------------------------
// Generic GEMM: C[M,N] = A[M,K] * B[K,N], row-major, bf16 MFMA, fp32 acc.
// A: fp32 or bf16 (templated). B: fp32. C: fp32 or bf16 (templated).
// M%64==0, N%64==0, K%32==0. If split64: output column c is remapped to
// (c>>6)*128 + (c&63) + coloff with row stride ldc (scatter H*64 -> H*128).
// ---------------------------------------------------------------------------
template <typename TA, typename TC>
__global__ __launch_bounds__(256) void gemm_kernel(
    const TA* __restrict__ A,
    const float* __restrict__ B,
    TC* __restrict__ C,
    int M, int N, int K, int ldc, int split64, int coloff)
{
    __shared__ alignas(16) __hip_bfloat16 As[64][40];   // 64 rows x 32 k (+pad)
    __shared__ alignas(16) __hip_bfloat16 Bt[64][40];   // 64 n x 32 k (+pad), transposed

    const int bn = blockIdx.x * 64;
    const int bm = blockIdx.y * 64;
    const int t = threadIdx.x;
    const int w = t >> 6;            // wave 0..3
    const int lane = t & 63;
    const int l15 = lane & 15;
    const int quad = lane >> 4;      // 0..3

    const int ar = t >> 2;           // 0..63
    const int ak = (t & 3) * 8;      // 0,8,16,24
    const int bk = t >> 3;           // 0..31
    const int bn0 = (t & 7) * 8;     // 0..56

    f32x4 acc[4] = {};

    for (int k0 = 0; k0 < K; k0 += 32) {
        // stage A tile (64x32)
        __hip_bfloat16 av[8];
        load8(&A[(size_t)(bm + ar) * K + k0 + ak], av);
        *reinterpret_cast<uint4*>(&As[ar][ak]) = *reinterpret_cast<uint4*>(av);
        // stage B tile (32x64) transposed into Bt[n][k]
        __hip_bfloat16 bv[8];
        load8(&B[(size_t)(k0 + bk) * N + bn + bn0], bv);
        #pragma unroll
        for (int j = 0; j < 8; j++) Bt[bn0 + j][bk] = bv[j];
        __syncthreads();

        // A fragment: A[m=l15][k=quad*8+j]
        bf16x8 af = ld_frag(&As[w * 16 + l15][quad * 8]);
        #pragma unroll
        for (int nt = 0; nt < 4; nt++) {
            // B fragment: B[k=quad*8+j][n=l15]  == Bt[n][k]
            bf16x8 bf = ld_frag(&Bt[nt * 16 + l15][quad * 8]);
            acc[nt] = __builtin_amdgcn_mfma_f32_16x16x32_bf16(af, bf, acc[nt], 0, 0, 0);
        }
        __syncthreads();
    }

    // epilogue: D[row=quad*4+r][col=l15]
    #pragma unroll
    for (int nt = 0; nt < 4; nt++) {
        #pragma unroll
        for (int r = 0; r < 4; r++) {
            int row = bm + w * 16 + quad * 4 + r;
            int col = bn + nt * 16 + l15;
            int oc = split64 ? (((col >> 6) * 128) + (col & 63) + coloff) : col;
            store_c(C, (size_t)row * ldc + oc, acc[nt][r]);
        }
    }
}

// ---------------------------------------------------------------------------
// RoPE + assemble: reads pre-rope k_r/q_r (BS x 1024 bf16, h-major x 64),
// writes rotated halves into K/Q buffers at [row*2048 + h*128 + 64 .. 128).
// ---------------------------------------------------------------------------
__global__ __launch_bounds__(256) void rope_assemble_kernel(
    const __hip_bfloat16* __restrict__ krp,
    const __hip_bfloat16* __restrict__ qrp,
    __hip_bfloat16* __restrict__ Kb,
    __hip_bfloat16* __restrict__ Qb)
{
    int idx = blockIdx.x * blockDim.x + threadIdx.x;
    if (idx >= BS * NH * 32) return;
    int i = idx & 31;              // freq index 0..31
    int h = (idx >> 5) & 15;
    int row = idx >> 9;            // b*S + s
    int s = row & (SS - 1);

    float inv = powf(10000.0f, -(float)i * (1.0f / 32.0f));
    float ang = (float)s * inv;
    float sn = sinf(ang), cs = cosf(ang);

    size_t pbase = (size_t)row * 1024 + h * 64 + i;
    size_t obase = (size_t)row * 2048 + h * 128 + 64 + i;
    {
        float x1 = __bfloat162float(krp[pbase]);
        float x2 = __bfloat162float(krp[pbase + 32]);
        Kb[obase]      = __float2bfloat16(x1 * cs - x2 * sn);
        Kb[obase + 32] = __float2bfloat16(x1 * sn + x2 * cs);
    }
    {
        float x1 = __bfloat162float(qrp[pbase]);
        float x2 = __bfloat162float(qrp[pbase + 32]);
        Qb[obase]      = __float2bfloat16(x1 * cs - x2 * sn);
        Qb[obase + 32] = __float2bfloat16(x1 * sn + x2 * cs);
    }
}

// ---------------------------------------------------------------------------
// Causal flash attention. Q/K/V layout (bf16): (b*S + s)*2048 + h*128 + d.
// Block = 256 threads (4 waves), 64 q-rows per block (16 per wave),
// kv tiles of 32, online softmax, MFMA for QK^T and PV.
// ---------------------------------------------------------------------------
__global__ __launch_bounds__(256) void flash_attn_kernel(
    const __hip_bfloat16* __restrict__ Q,
    const __hip_bfloat16* __restrict__ Kb,
    const __hip_bfloat16* __restrict__ Vb,
    __hip_bfloat16* __restrict__ O)
{
    __shared__ alignas(16) __hip_bfloat16 Kt[32][136];   // [kv][d]
    __shared__ alignas(16) __hip_bfloat16 Vt[128][40];   // [d][kv] transposed
    __shared__ alignas(16) __hip_bfloat16 Sp[4][16][32]; // per-wave P [q][kv]

    const int qt = blockIdx.x;      // 0..31
    const int h = blockIdx.y;       // 0..15
    const int b = blockIdx.z;       // 0..1
    const int t = threadIdx.x;
    const int w = t >> 6;
    const int lane = t & 63;
    const int l15 = lane & 15;
    const int quad = lane >> 4;
    const int qbase = qt * 64;

    // preload Q fragments: Q[m=l15][d = ds*32 + quad*8 + j]
    bf16x8 qf[4];
    {
        const __hip_bfloat16* qrow =
            Q + (size_t)(b * SS + qbase + w * 16 + l15) * 2048 + h * 128;
        #pragma unroll
        for (int ds = 0; ds < 4; ds++) qf[ds] = ld_frag(qrow + ds * 32 + quad * 8);
    }

    float m_i[4], l_i[4];
    f32x4 acc[8] = {};
    #pragma unroll
    for (int r = 0; r < 4; r++) { m_i[r] = -INFINITY; l_i[r] = 0.0f; }

    const int ktiles = qbase / 32 + 2;    // covers kv <= qbase+63
    const int srow = t >> 3;              // 0..31
    const int scol = (t & 7) * 16;        // 0..112

    for (int kt = 0; kt < ktiles; kt++) {
        const int kvbase = kt * 32;
        // stage K (direct) and V (transposed)
        {
            const __hip_bfloat16* kp =
                Kb + (size_t)(b * SS + kvbase + srow) * 2048 + h * 128 + scol;
            uint4 k0 = *reinterpret_cast<const uint4*>(kp);
            uint4 k1 = *reinterpret_cast<const uint4*>(kp + 8);
            *reinterpret_cast<uint4*>(&Kt[srow][scol]) = k0;
            *reinterpret_cast<uint4*>(&Kt[srow][scol + 8]) = k1;
            const __hip_bfloat16* vp =
                Vb + (size_t)(b * SS + kvbase + srow) * 2048 + h * 128 + scol;
            uint4 v0 = *reinterpret_cast<const uint4*>(vp);
            uint4 v1 = *reinterpret_cast<const uint4*>(vp + 8);
            const __hip_bfloat16* ve = reinterpret_cast<const __hip_bfloat16*>(&v0);
            #pragma unroll
            for (int j = 0; j < 8; j++) Vt[scol + j][srow] = ve[j];
            ve = reinterpret_cast<const __hip_bfloat16*>(&v1);
            #pragma unroll
            for (int j = 0; j < 8; j++) Vt[scol + 8 + j][srow] = ve[j];
        }
        __syncthreads();

        // S = Q * K^T for two 16-wide kv halves, scaled + causal-masked
        float sv[2][4];
        #pragma unroll
        for (int half = 0; half < 2; half++) {
            f32x4 s = {};
            #pragma unroll
            for (int ds = 0; ds < 4; ds++) {
                bf16x8 kf = ld_frag(&Kt[half * 16 + l15][ds * 32 + quad * 8]);
                s = __builtin_amdgcn_mfma_f32_16x16x32_bf16(qf[ds], kf, s, 0, 0, 0);
            }
            int kv = kvbase + half * 16 + l15;
            #pragma unroll
            for (int r = 0; r < 4; r++) {
                int qrow = qbase + w * 16 + quad * 4 + r;
                float x = s[r] * SCALE;
                sv[half][r] = (kv <= qrow) ? x : -1e30f;
            }
        }

        // online softmax per q-row (row q = quad*4+r, spread over 16 lanes)
        float alpha[4];
        #pragma unroll
        for (int r = 0; r < 4; r++) {
            float tm = fmaxf(sv[0][r], sv[1][r]);
            #pragma unroll
            for (int off = 1; off < 16; off <<= 1) tm = fmaxf(tm, __shfl_xor(tm, off));
            float mnew = fmaxf(m_i[r], tm);
            float p0 = __expf(sv[0][r] - mnew);
            float p1 = __expf(sv[1][r] - mnew);
            float rs = p0 + p1;
            #pragma unroll
            for (int off = 1; off < 16; off <<= 1) rs += __shfl_xor(rs, off);
            alpha[r] = __expf(m_i[r] - mnew);
            l_i[r] = l_i[r] * alpha[r] + rs;
            m_i[r] = mnew;
            Sp[w][quad * 4 + r][l15]      = __float2bfloat16(p0);
            Sp[w][quad * 4 + r][16 + l15] = __float2bfloat16(p1);
        }
        // rescale O accumulator (C-layout rows match r)
        #pragma unroll
        for (int dt = 0; dt < 8; dt++) {
            #pragma unroll
            for (int r = 0; r < 4; r++) acc[dt][r] *= alpha[r];
        }
        __syncthreads();

        // PV: A = P (Sp, A-layout), B = V tile -> acc += P*V
        bf16x8 pf = ld_frag(&Sp[w][l15][quad * 8]);
        #pragma unroll
        for (int dt = 0; dt < 8; dt++) {
            bf16x8 vf = ld_frag(&Vt[dt * 16 + l15][quad * 8]);
            acc[dt] = __builtin_amdgcn_mfma_f32_16x16x32_bf16(pf, vf, acc[dt], 0, 0, 0);
        }
        __syncthreads();
    }

    // epilogue: O = acc / l
    #pragma unroll
    for (int r = 0; r < 4; r++) {
        int qrow = qbase + w * 16 + quad * 4 + r;
        __hip_bfloat16* orow = O + (size_t)(b * SS + qrow) * 2048 + h * 128;
        float inv_l = 1.0f / l_i[r];
        #pragma unroll
        for (int dt = 0; dt < 8; dt++) {
            orow[dt * 16 + l15] = __float2bfloat16(acc[dt][r] * inv_l);
        }
    }
}

// ---------------------------------------------------------------------------
extern "C" void kernel_launch(void* const* d_in, const int* in_sizes, int n_in,
                              void* d_out, int out_size, void* d_ws, size_t ws_size,
                              hipStream_t stream)
{
    // Reference dtypes are float32 for ALL inputs and the output.
    const float* hs       = (const float*)d_in[0];
    const float* w_kv_d   = (const float*)d_in[1];
    const float* w_q_d    = (const float*)d_in[2];
    const float* w_k_u    = (const float*)d_in[3];
    const float* w_q_u    = (const float*)d_in[4];
    const float* w_v_u    = (const float*)d_in[5];
    const float* w_rope_k = (const float*)d_in[6];
    const float* w_rope_q = (const float*)d_in[7];
    const float* w_o      = (const float*)d_in[8];
    float* out = (float*)d_out;

    char* p = (char*)d_ws;
    auto alloc = [&](size_t nelem) {
        __hip_bfloat16* r = (__hip_bfloat16*)p;
        p += nelem * sizeof(__hip_bfloat16);
        return r;
    };
    __hip_bfloat16* kv_d = alloc((size_t)BS * LAT);      // 2 MB
    __hip_bfloat16* q_d  = alloc((size_t)BS * LAT);      // 2 MB
    __hip_bfloat16* Kbuf = alloc((size_t)BS * HID);      // 16 MB
    __hip_bfloat16* Qbuf = alloc((size_t)BS * HID);      // 16 MB
    __hip_bfloat16* Vbuf = alloc((size_t)BS * HID);      // 16 MB
    __hip_bfloat16* attn = alloc((size_t)BS * HID);      // 16 MB
    __hip_bfloat16* krp  = alloc((size_t)BS * 1024);     // 8 MB
    __hip_bfloat16* qrp  = alloc((size_t)BS * 1024);     // 8 MB

    dim3 blk(256);

    // 1. kv_d = hs @ w_kv_d            (4096 x 256, K=2048)
    gemm_kernel<float, __hip_bfloat16><<<dim3(256/64, BS/64), blk, 0, stream>>>(
        hs, w_kv_d, kv_d, BS, 256, 2048, 256, 0, 0);
    // 2. q_d = hs @ w_q_d
    gemm_kernel<float, __hip_bfloat16><<<dim3(256/64, BS/64), blk, 0, stream>>>(
        hs, w_q_d, q_d, BS, 256, 2048, 256, 0, 0);
    // 3. krp = hs @ w_rope_k           (4096 x 1024, K=2048)
    gemm_kernel<float, __hip_bfloat16><<<dim3(1024/64, BS/64), blk, 0, stream>>>(
        hs, w_rope_k, krp, BS, 1024, 2048, 1024, 0, 0);
    // 4. Kbuf[.., h*128+0..64) = kv_d @ w_k_u   (split64 scatter)
    gemm_kernel<__hip_bfloat16, __hip_bfloat16><<<dim3(1024/64, BS/64), blk, 0, stream>>>(
        kv_d, w_k_u, Kbuf, BS, 1024, 256, 2048, 1, 0);
    // 5. Vbuf = kv_d @ w_v_u           (4096 x 2048, K=256)
    gemm_kernel<__hip_bfloat16, __hip_bfloat16><<<dim3(2048/64, BS/64), blk, 0, stream>>>(
        kv_d, w_v_u, Vbuf, BS, 2048, 256, 2048, 0, 0);
    // 6. Qbuf[.., h*128+0..64) = q_d @ w_q_u    (split64 scatter)
    gemm_kernel<__hip_bfloat16, __hip_bfloat16><<<dim3(1024/64, BS/64), blk, 0, stream>>>(
        q_d, w_q_u, Qbuf, BS, 1024, 256, 2048, 1, 0);
    // 7. qrp = q_d @ w_rope_q
    gemm_kernel<__hip_bfloat16, __hip_bfloat16><<<dim3(1024/64, BS/64), blk, 0, stream>>>(
        q_d, w_rope_q, qrp, BS, 1024, 256, 1024, 0, 0);
    // 8. RoPE + assemble rope halves of K/Q
    rope_assemble_kernel<<<dim3((BS * NH * 32 + 255) / 256), blk, 0, stream>>>(
        krp, qrp, Kbuf, Qbuf);
    // 9. causal flash attention -> attn
    flash_attn_kernel<<<dim3(SS/64, NH, BB), blk, 0, stream>>>(
        Qbuf, Kbuf, Vbuf, attn);
    // 10. out = attn @ w_o             (4096 x 2048, K=2048), fp32 output
    gemm_kernel<__hip_bfloat16, float><<<dim3(2048/64, BS/64), blk, 0, stream>>>(
        attn, w_o, out, BS, 2048, 2048, 2048, 0, 0);
}

// Round 4
// 605.959 us; speedup vs baseline: 1.4667x; 1.4667x over previous
//
#include <hip/hip_runtime.h>
#include <hip/hip_bf16.h>

// Problem constants: B=2, S=2048, HID=2048, H=16, HD=128, HD2=64, LAT=256
#define BB 2
#define SS 2048
#define HID 2048
#define NH 16
#define BS (BB*SS)          // 4096 rows
#define SCALE 0.088388347648318447f   // 1/sqrt(128)

typedef __bf16 bf16x8 __attribute__((ext_vector_type(8)));
typedef float f32x4 __attribute__((ext_vector_type(4)));

__device__ __forceinline__ bf16x8 ld_frag(const __hip_bfloat16* p) {
    uint4 u = *reinterpret_cast<const uint4*>(p);
    return __builtin_bit_cast(bf16x8, u);
}
__device__ __forceinline__ void store_c(__hip_bfloat16* C, size_t idx, float v) {
    C[idx] = __float2bfloat16(v);
}
__device__ __forceinline__ void store_c(float* C, size_t idx, float v) {
    C[idx] = v;
}
__device__ __forceinline__ ushort bf_bits(float v) {
    __hip_bfloat16 h = __float2bfloat16(v);
    return *reinterpret_cast<ushort*>(&h);
}

// async global->LDS, 16B per lane; lds addrs must be wave-uniform base + lane*16
#define GLD16(gp, lp) \
  __builtin_amdgcn_global_load_lds((const __attribute__((address_space(1))) void*)(gp), \
                                   (__attribute__((address_space(3))) void*)(lp), 16, 0, 0)

// ---------------------------------------------------------------------------
// fp32 -> bf16 flat convert (hs)
// ---------------------------------------------------------------------------
__global__ __launch_bounds__(256) void convert_kernel(
    const float* __restrict__ src, __hip_bfloat16* __restrict__ dst, int n8)
{
    int i = blockIdx.x * blockDim.x + threadIdx.x;
    if (i >= n8) return;
    float4 a = reinterpret_cast<const float4*>(src)[2 * i];
    float4 b = reinterpret_cast<const float4*>(src)[2 * i + 1];
    ushort u[8] = { bf_bits(a.x), bf_bits(a.y), bf_bits(a.z), bf_bits(a.w),
                    bf_bits(b.x), bf_bits(b.y), bf_bits(b.z), bf_bits(b.w) };
    reinterpret_cast<uint4*>(dst)[i] = *reinterpret_cast<uint4*>(u);
}

// ---------------------------------------------------------------------------
// Fused weight transpose+convert: 8 segments, src fp32 [R][C] -> dst bf16 [C][R]
// ---------------------------------------------------------------------------
__global__ __launch_bounds__(256) void transpose_weights_kernel(
    const float* s0, const float* s1, const float* s2, const float* s3,
    const float* s4, const float* s5, const float* s6, const float* s7,
    __hip_bfloat16* WT1, __hip_bfloat16* WT2, __hip_bfloat16* WT3,
    __hip_bfloat16* WTo)
{
    const float* srcs[8] = { s0, s1, s2, s3, s4, s5, s6, s7 };
    const int Rs[8] = { 2048, 2048, 2048, 256, 256, 256, 256, 2048 };
    const int Cs[8] = { 256, 256, 1024, 1024, 2048, 1024, 1024, 2048 };
    __hip_bfloat16* dsts[8] = {
        WT1, WT1 + (size_t)256 * 2048, WT1 + (size_t)512 * 2048,
        WT2, WT2 + (size_t)1024 * 256,
        WT3, WT3 + (size_t)1024 * 256,
        WTo };
    const int prefix[9] = { 0, 512, 1024, 3072, 3328, 3840, 4096, 4352, 8448 };

    int bid = blockIdx.x;
    int seg = 0;
    #pragma unroll
    for (int i = 0; i < 8; i++) if (bid >= prefix[i + 1]) seg = i + 1;
    int local = bid - prefix[seg];
    int R = Rs[seg], C = Cs[seg];
    int tilesC = C / 32;
    int tr = local / tilesC, tc = local % tilesC;
    int r0 = tr * 32, c0 = tc * 32;
    const float* src = srcs[seg];
    __hip_bfloat16* dst = dsts[seg];

    __shared__ float Ts[32][33];
    int t = threadIdx.x;
    int ty = t >> 5, tx = t & 31;
    #pragma unroll
    for (int k = 0; k < 4; k++) {
        int r = ty + k * 8;
        Ts[r][tx] = src[(size_t)(r0 + r) * C + c0 + tx];
    }
    __syncthreads();
    #pragma unroll
    for (int k = 0; k < 4; k++) {
        int r = ty + k * 8;
        dst[(size_t)(c0 + r) * R + r0 + tx] = __float2bfloat16(Ts[tx][r]);
    }
}

// ---------------------------------------------------------------------------
// m97-style GEMM: C = A[M,K] * Bt[N,K]^T, bf16 in, fp32 acc.
// 128x128 tile, BK=32, global_load_lds staging, 4 waves each 64x64.
// Two-destination epilogue: col < splitN -> C0 else C1 (col-splitN);
// s64 flag remaps column c -> (c>>6)*128 + (c&63) + off (head scatter).
// ---------------------------------------------------------------------------
template <typename TC>
__global__ __launch_bounds__(256) void gemm_bt_kernel(
    const __hip_bfloat16* __restrict__ A, int lda,
    const __hip_bfloat16* __restrict__ Bt,
    TC* __restrict__ C0, int ldc0, int sp0, int off0,
    TC* __restrict__ C1, int ldc1, int sp1, int off1,
    int splitN, int K)
{
    __shared__ alignas(16) __hip_bfloat16 As[128 * 32];
    __shared__ alignas(16) __hip_bfloat16 Bs[128 * 32];

    const int bn = blockIdx.x * 128;
    const int bm = blockIdx.y * 128;
    const int t = threadIdx.x;
    const int w = t >> 6;
    const int lane = t & 63;
    const int l15 = lane & 15;
    const int quad = lane >> 4;
    const int wm = (w & 1) * 64;
    const int wn = (w >> 1) * 64;

    const int srow = lane >> 2;          // 0..15
    const int skcol = (lane & 3) * 8;    // 0,8,16,24

    f32x4 acc[4][4] = {};

    for (int k0 = 0; k0 < K; k0 += 32) {
        __syncthreads();   // protect LDS from overwrite while prev iter reads
        #pragma unroll
        for (int i = 0; i < 2; i++) {
            int r = w * 32 + i * 16 + srow;
            GLD16(A + (size_t)(bm + r) * lda + k0 + skcol, &As[r * 32 + skcol]);
            GLD16(Bt + (size_t)(bn + r) * K + k0 + skcol, &Bs[r * 32 + skcol]);
        }
        __syncthreads();   // loads complete & visible

        bf16x8 af[4], bf[4];
        #pragma unroll
        for (int mt = 0; mt < 4; mt++)
            af[mt] = ld_frag(&As[(wm + mt * 16 + l15) * 32 + quad * 8]);
        #pragma unroll
        for (int nt = 0; nt < 4; nt++)
            bf[nt] = ld_frag(&Bs[(wn + nt * 16 + l15) * 32 + quad * 8]);
        #pragma unroll
        for (int mt = 0; mt < 4; mt++)
            #pragma unroll
            for (int nt = 0; nt < 4; nt++)
                acc[mt][nt] = __builtin_amdgcn_mfma_f32_16x16x32_bf16(
                    af[mt], bf[nt], acc[mt][nt], 0, 0, 0);
    }

    // epilogue with routing
    #pragma unroll
    for (int nt = 0; nt < 4; nt++) {
        int col = bn + wn + nt * 16 + l15;
        TC* Cp; int c, ld, s64, off;
        if (col < splitN) { Cp = C0; c = col; ld = ldc0; s64 = sp0; off = off0; }
        else { Cp = C1; c = col - splitN; ld = ldc1; s64 = sp1; off = off1; }
        int oc = s64 ? ((c >> 6) * 128 + (c & 63) + off) : c;
        #pragma unroll
        for (int mt = 0; mt < 4; mt++) {
            #pragma unroll
            for (int r = 0; r < 4; r++) {
                int row = bm + wm + mt * 16 + quad * 4 + r;
                store_c(Cp, (size_t)row * ld + oc, acc[mt][nt][r]);
            }
        }
    }
}

// ---------------------------------------------------------------------------
// RoPE in-place on K/Q rope halves: cols h*128+64+i and h*128+96+i rotated.
// ---------------------------------------------------------------------------
__global__ __launch_bounds__(256) void rope_kernel(
    __hip_bfloat16* __restrict__ Kb, __hip_bfloat16* __restrict__ Qb)
{
    int idx = blockIdx.x * blockDim.x + threadIdx.x;
    if (idx >= BS * NH * 32) return;
    int i = idx & 31;
    int h = (idx >> 5) & 15;
    int row = idx >> 9;
    int s = row & (SS - 1);

    float inv = exp2f(-(float)i * 0.4152410118609203f);  // 10000^(-i/32)
    float ang = (float)s * inv;
    float sn = sinf(ang), cs = cosf(ang);

    size_t obase = (size_t)row * 2048 + h * 128 + 64 + i;
    {
        float x1 = __bfloat162float(Kb[obase]);
        float x2 = __bfloat162float(Kb[obase + 32]);
        Kb[obase]      = __float2bfloat16(x1 * cs - x2 * sn);
        Kb[obase + 32] = __float2bfloat16(x1 * sn + x2 * cs);
    }
    {
        float x1 = __bfloat162float(Qb[obase]);
        float x2 = __bfloat162float(Qb[obase + 32]);
        Qb[obase]      = __float2bfloat16(x1 * cs - x2 * sn);
        Qb[obase + 32] = __float2bfloat16(x1 * sn + x2 * cs);
    }
}

// ---------------------------------------------------------------------------
// Flash attention v3: S^T = K*Q^T (both operands direct from global, natural
// layout), per-lane softmax (q = l15), P->LDS->A-frag, PV with V staged as
// packed dwords [d][kv] pitch 40 dw (conflict-free writes & reads).
// kv-tile = 64, 2 barriers per tile. Block: 256 thr, 64 q rows.
// ---------------------------------------------------------------------------
__global__ __launch_bounds__(256) void flash_attn_kernel(
    const __hip_bfloat16* __restrict__ Q,
    const __hip_bfloat16* __restrict__ Kb,
    const __hip_bfloat16* __restrict__ Vb,
    __hip_bfloat16* __restrict__ O)
{
    __shared__ uint Vt4[128 * 40];          // [d][kv pair-dwords], pitch 40 dw
    __shared__ ushort Sp[4][16 * 80];       // per-wave P [q][kv], pitch 80

    const int qt = 31 - blockIdx.x;         // big blocks dispatched first
    const int h = blockIdx.y;
    const int b = blockIdx.z;
    const int t = threadIdx.x;
    const int w = t >> 6;
    const int lane = t & 63;
    const int l15 = lane & 15;
    const int quad = lane >> 4;
    const int qbase = qt * 64;
    const int q = qbase + w * 16 + l15;     // this lane's q row (softmax view)

    const __hip_bfloat16* Kbase = Kb + (size_t)(b * SS) * 2048 + h * 128;
    const __hip_bfloat16* Vbase = Vb + (size_t)(b * SS) * 2048 + h * 128;

    // Q B-frags: Q[q=l15][d = ds*32 + quad*8 + j]
    bf16x8 qf[4];
    {
        const __hip_bfloat16* qrow = Q + (size_t)(b * SS + q) * 2048 + h * 128;
        #pragma unroll
        for (int ds = 0; ds < 4; ds++) qf[ds] = ld_frag(qrow + ds * 32 + quad * 8);
    }

    float m_i = -INFINITY, l_i = 0.0f;      // per-lane (q = l15), quad-replicated
    f32x4 acc[8] = {};

    const int k2 = t & 31;                  // kv pair index
    const int dbase = (t >> 5) * 16;        // 8 groups x 16 d
    const int ntiles = qt + 1;

    for (int kt = 0; kt < ntiles; kt++) {
        const int kvbase = kt * 64;
        if (kt) __syncthreads();            // protect Vt/Sp from overwrite

        // ---- stage V tile (64 kv x 128 d) as packed dwords [d][kv] ----
        {
            const __hip_bfloat16* v0 = Vbase + (size_t)(kvbase + 2 * k2) * 2048 + dbase;
            uint4 a0 = *reinterpret_cast<const uint4*>(v0);
            uint4 a1 = *reinterpret_cast<const uint4*>(v0 + 8);
            uint4 b0 = *reinterpret_cast<const uint4*>(v0 + 2048);
            uint4 b1 = *reinterpret_cast<const uint4*>(v0 + 2056);
            const ushort* pa = reinterpret_cast<const ushort*>(&a0);
            const ushort* pb = reinterpret_cast<const ushort*>(&b0);
            #pragma unroll
            for (int j = 0; j < 8; j++)
                Vt4[(dbase + j) * 40 + k2] = (uint)pa[j] | ((uint)pb[j] << 16);
            pa = reinterpret_cast<const ushort*>(&a1);
            pb = reinterpret_cast<const ushort*>(&b1);
            #pragma unroll
            for (int j = 0; j < 8; j++)
                Vt4[(dbase + 8 + j) * 40 + k2] = (uint)pa[j] | ((uint)pb[j] << 16);
        }

        // ---- S^T = K * Q^T : A-frag = K rows direct from global ----
        f32x4 st[4];
        #pragma unroll
        for (int kvsub = 0; kvsub < 4; kvsub++) {
            f32x4 s = {};
            const __hip_bfloat16* krow =
                Kbase + (size_t)(kvbase + kvsub * 16 + l15) * 2048;
            #pragma unroll
            for (int ds = 0; ds < 4; ds++) {
                bf16x8 kf = ld_frag(krow + ds * 32 + quad * 8);
                s = __builtin_amdgcn_mfma_f32_16x16x32_bf16(kf, qf[ds], s, 0, 0, 0);
            }
            #pragma unroll
            for (int r = 0; r < 4; r++) {
                int kv = kvbase + kvsub * 16 + quad * 4 + r;
                st[kvsub][r] = (kv <= q) ? s[r] * SCALE : -INFINITY;
            }
        }

        // ---- online softmax: in-lane over 16, cross-quad via 2 shuffles ----
        float tm = st[0][0];
        #pragma unroll
        for (int kvsub = 0; kvsub < 4; kvsub++)
            #pragma unroll
            for (int r = 0; r < 4; r++) tm = fmaxf(tm, st[kvsub][r]);
        tm = fmaxf(tm, __shfl_xor(tm, 16));
        tm = fmaxf(tm, __shfl_xor(tm, 32));
        float mnew = fmaxf(m_i, tm);
        float rs = 0.0f;
        #pragma unroll
        for (int kvsub = 0; kvsub < 4; kvsub++)
            #pragma unroll
            for (int r = 0; r < 4; r++) {
                float pv = __expf(st[kvsub][r] - mnew);
                st[kvsub][r] = pv;
                rs += pv;
            }
        rs += __shfl_xor(rs, 16);
        rs += __shfl_xor(rs, 32);
        float alpha = __expf(m_i - mnew);
        m_i = mnew;
        l_i = l_i * alpha + rs;

        // ---- write P to Sp (b64: 4 consecutive kv per store) ----
        #pragma unroll
        for (int kvsub = 0; kvsub < 4; kvsub++) {
            ushort pk[4] = { bf_bits(st[kvsub][0]), bf_bits(st[kvsub][1]),
                             bf_bits(st[kvsub][2]), bf_bits(st[kvsub][3]) };
            *reinterpret_cast<uint2*>(&Sp[w][l15 * 80 + kvsub * 16 + quad * 4]) =
                *reinterpret_cast<uint2*>(pk);
        }

        // ---- rescale O accumulator: alpha for row q-local = quad*4+r ----
        float al[4];
        #pragma unroll
        for (int r = 0; r < 4; r++) al[r] = __shfl(alpha, quad * 4 + r, 64);
        #pragma unroll
        for (int dt = 0; dt < 8; dt++)
            #pragma unroll
            for (int r = 0; r < 4; r++) acc[dt][r] *= al[r];

        __syncthreads();    // Vt + Sp visible

        // ---- PV: A = P (Sp), B = V (Vt) ----
        bf16x8 pf0 = ld_frag(reinterpret_cast<const __hip_bfloat16*>(
            &Sp[w][l15 * 80 + quad * 8]));
        bf16x8 pf1 = ld_frag(reinterpret_cast<const __hip_bfloat16*>(
            &Sp[w][l15 * 80 + 32 + quad * 8]));
        #pragma unroll
        for (int dt = 0; dt < 8; dt++) {
            const __hip_bfloat16* vrow =
                reinterpret_cast<const __hip_bfloat16*>(&Vt4[(dt * 16 + l15) * 40]);
            acc[dt] = __builtin_amdgcn_mfma_f32_16x16x32_bf16(
                pf0, ld_frag(vrow + quad * 8), acc[dt], 0, 0, 0);
            acc[dt] = __builtin_amdgcn_mfma_f32_16x16x32_bf16(
                pf1, ld_frag(vrow + 32 + quad * 8), acc[dt], 0, 0, 0);
        }
    }

    // ---- epilogue: O rows = qbase + w*16 + quad*4 + r, cols dt*16 + l15 ----
    float li[4];
    #pragma unroll
    for (int r = 0; r < 4; r++) li[r] = __shfl(l_i, quad * 4 + r, 64);
    #pragma unroll
    for (int r = 0; r < 4; r++) {
        int row = qbase + w * 16 + quad * 4 + r;
        __hip_bfloat16* orow = O + (size_t)(b * SS + row) * 2048 + h * 128;
        float inv_l = 1.0f / li[r];
        #pragma unroll
        for (int dt = 0; dt < 8; dt++)
            orow[dt * 16 + l15] = __float2bfloat16(acc[dt][r] * inv_l);
    }
}

// ---------------------------------------------------------------------------
extern "C" void kernel_launch(void* const* d_in, const int* in_sizes, int n_in,
                              void* d_out, int out_size, void* d_ws, size_t ws_size,
                              hipStream_t stream)
{
    const float* hs       = (const float*)d_in[0];
    const float* w_kv_d   = (const float*)d_in[1];
    const float* w_q_d    = (const float*)d_in[2];
    const float* w_k_u    = (const float*)d_in[3];
    const float* w_q_u    = (const float*)d_in[4];
    const float* w_v_u    = (const float*)d_in[5];
    const float* w_rope_k = (const float*)d_in[6];
    const float* w_rope_q = (const float*)d_in[7];
    const float* w_o      = (const float*)d_in[8];
    float* out = (float*)d_out;

    char* p = (char*)d_ws;
    auto alloc = [&](size_t nelem) {
        __hip_bfloat16* r = (__hip_bfloat16*)p;
        p += nelem * sizeof(__hip_bfloat16);
        return r;
    };
    __hip_bfloat16* hsb  = alloc((size_t)BS * HID);        // 16 MB (reused as attn)
    __hip_bfloat16* qkvd = alloc((size_t)BS * 512);        // 4 MB
    __hip_bfloat16* WT1  = alloc((size_t)1536 * 2048);     // 6 MB
    __hip_bfloat16* WT2  = alloc((size_t)3072 * 256);      // 1.5 MB
    __hip_bfloat16* WT3  = alloc((size_t)2048 * 256);      // 1 MB
    __hip_bfloat16* WTo  = alloc((size_t)2048 * 2048);     // 8 MB
    __hip_bfloat16* Kbuf = alloc((size_t)BS * HID);        // 16 MB
    __hip_bfloat16* Qbuf = alloc((size_t)BS * HID);        // 16 MB
    __hip_bfloat16* Vbuf = alloc((size_t)BS * HID);        // 16 MB
    __hip_bfloat16* attn = hsb;   // hs dead after G1

    dim3 blk(256);

    // 0a. hs -> bf16
    convert_kernel<<<dim3((BS * HID / 8 + 255) / 256), blk, 0, stream>>>(
        hs, hsb, BS * HID / 8);
    // 0b. all weights: transpose + convert to bf16 W^T
    transpose_weights_kernel<<<dim3(8448), blk, 0, stream>>>(
        w_kv_d, w_q_d, w_rope_k, w_k_u, w_v_u, w_q_u, w_rope_q, w_o,
        WT1, WT2, WT3, WTo);

    // G1: [kv_d | q_d | krp] = hsb @ WT1^T  (N=1536, K=2048)
    //     cols 0..511 -> qkvd plain; cols 512..1535 -> Kbuf rope half (coloff 64)
    gemm_bt_kernel<__hip_bfloat16><<<dim3(1536 / 128, BS / 128), blk, 0, stream>>>(
        hsb, 2048, WT1,
        qkvd, 512, 0, 0,
        Kbuf, 2048, 1, 64,
        512, 2048);
    // G2: [k_p | v] = kv_d @ WT2^T  (N=3072, K=256)
    //     cols 0..1023 -> Kbuf nope half (split64); cols 1024..3071 -> Vbuf plain
    gemm_bt_kernel<__hip_bfloat16><<<dim3(3072 / 128, BS / 128), blk, 0, stream>>>(
        qkvd, 512, WT2,
        Kbuf, 2048, 1, 0,
        Vbuf, 2048, 0, 0,
        1024, 256);
    // G3: [q_p | q_rope_pre] = q_d @ WT3^T  (N=2048, K=256)
    //     cols 0..1023 -> Qbuf nope half; 1024..2047 -> Qbuf rope half (pre-rope)
    gemm_bt_kernel<__hip_bfloat16><<<dim3(2048 / 128, BS / 128), blk, 0, stream>>>(
        qkvd + 256, 512, WT3,
        Qbuf, 2048, 1, 0,
        Qbuf, 2048, 1, 64,
        1024, 256);
    // 4. RoPE in-place on K/Q rope halves
    rope_kernel<<<dim3((BS * NH * 32 + 255) / 256), blk, 0, stream>>>(Kbuf, Qbuf);
    // 5. flash attention -> attn
    flash_attn_kernel<<<dim3(SS / 64, NH, BB), blk, 0, stream>>>(
        Qbuf, Kbuf, Vbuf, attn);
    // G4: out = attn @ WTo^T (fp32 out)
    gemm_bt_kernel<float><<<dim3(2048 / 128, BS / 128), blk, 0, stream>>>(
        attn, 2048, WTo,
        out, 2048, 0, 0,
        out, 2048, 0, 0,
        2048, 2048);
}

// Round 5
// 387.610 us; speedup vs baseline: 2.2929x; 1.5633x over previous
//
#include <hip/hip_runtime.h>
#include <hip/hip_bf16.h>

// Problem constants: B=2, S=2048, HID=2048, H=16, HD=128, HD2=64, LAT=256
#define BB 2
#define SS 2048
#define HID 2048
#define NH 16
#define BS (BB*SS)          // 4096 rows
#define SCALE 0.088388347648318447f   // 1/sqrt(128)

typedef __bf16 bf16x8 __attribute__((ext_vector_type(8)));
typedef float f32x4 __attribute__((ext_vector_type(4)));

__device__ __forceinline__ bf16x8 ld_frag(const __hip_bfloat16* p) {
    uint4 u = *reinterpret_cast<const uint4*>(p);
    return __builtin_bit_cast(bf16x8, u);
}
__device__ __forceinline__ void store_c(__hip_bfloat16* C, size_t idx, float v) {
    C[idx] = __float2bfloat16(v);
}
__device__ __forceinline__ void store_c(float* C, size_t idx, float v) {
    C[idx] = v;
}
__device__ __forceinline__ ushort bf_bits(float v) {
    __hip_bfloat16 h = __float2bfloat16(v);
    return *reinterpret_cast<ushort*>(&h);
}

// async global->LDS, 16B per lane; lds addr must be wave-uniform base + lane*16
#define GLD16(gp, lp) \
  __builtin_amdgcn_global_load_lds((const __attribute__((address_space(1))) void*)(gp), \
                                   (__attribute__((address_space(3))) void*)(lp), 16, 0, 0)

// ---------------------------------------------------------------------------
// fp32 -> bf16 flat convert (hs)
// ---------------------------------------------------------------------------
__global__ __launch_bounds__(256) void convert_kernel(
    const float* __restrict__ src, __hip_bfloat16* __restrict__ dst, int n8)
{
    int i = blockIdx.x * blockDim.x + threadIdx.x;
    if (i >= n8) return;
    float4 a = reinterpret_cast<const float4*>(src)[2 * i];
    float4 b = reinterpret_cast<const float4*>(src)[2 * i + 1];
    ushort u[8] = { bf_bits(a.x), bf_bits(a.y), bf_bits(a.z), bf_bits(a.w),
                    bf_bits(b.x), bf_bits(b.y), bf_bits(b.z), bf_bits(b.w) };
    reinterpret_cast<uint4*>(dst)[i] = *reinterpret_cast<uint4*>(u);
}

// ---------------------------------------------------------------------------
// Fused weight transpose+convert: 8 segments, src fp32 [R][C] -> dst bf16 [C][R]
// ---------------------------------------------------------------------------
__global__ __launch_bounds__(256) void transpose_weights_kernel(
    const float* s0, const float* s1, const float* s2, const float* s3,
    const float* s4, const float* s5, const float* s6, const float* s7,
    __hip_bfloat16* WT1, __hip_bfloat16* WT2, __hip_bfloat16* WT3,
    __hip_bfloat16* WTo)
{
    const float* srcs[8] = { s0, s1, s2, s3, s4, s5, s6, s7 };
    const int Rs[8] = { 2048, 2048, 2048, 256, 256, 256, 256, 2048 };
    const int Cs[8] = { 256, 256, 1024, 1024, 2048, 1024, 1024, 2048 };
    __hip_bfloat16* dsts[8] = {
        WT1, WT1 + (size_t)256 * 2048, WT1 + (size_t)512 * 2048,
        WT2, WT2 + (size_t)1024 * 256,
        WT3, WT3 + (size_t)1024 * 256,
        WTo };
    const int prefix[9] = { 0, 512, 1024, 3072, 3328, 3840, 4096, 4352, 8448 };

    int bid = blockIdx.x;
    int seg = 0;
    #pragma unroll
    for (int i = 0; i < 8; i++) if (bid >= prefix[i + 1]) seg = i + 1;
    int local = bid - prefix[seg];
    int R = Rs[seg], C = Cs[seg];
    int tilesC = C / 32;
    int tr = local / tilesC, tc = local % tilesC;
    int r0 = tr * 32, c0 = tc * 32;
    const float* src = srcs[seg];
    __hip_bfloat16* dst = dsts[seg];

    __shared__ float Ts[32][33];
    int t = threadIdx.x;
    int ty = t >> 5, tx = t & 31;
    #pragma unroll
    for (int k = 0; k < 4; k++) {
        int r = ty + k * 8;
        Ts[r][tx] = src[(size_t)(r0 + r) * C + c0 + tx];
    }
    __syncthreads();
    #pragma unroll
    for (int k = 0; k < 4; k++) {
        int r = ty + k * 8;
        dst[(size_t)(c0 + r) * R + r0 + tx] = __float2bfloat16(Ts[tx][r]);
    }
}

// ---------------------------------------------------------------------------
// m97-style GEMM: C = A[M,K] * Bt[N,K]^T, bf16 in, fp32 acc.
// 128x128 tile, BK=32, global_load_lds staging, 4 waves each 64x64.
// Epilogue routing: col < splitN -> (C0,...) else (C1,...).
//   s64==0: plain col;  s64==1: col c -> (c>>6)*128 + (c&63) + off (head scatter)
//   s64==2: transposed store: Cp[(size_t)c*4096 + row]  (V-transpose for flash)
// ---------------------------------------------------------------------------
template <typename TC>
__global__ __launch_bounds__(256) void gemm_bt_kernel(
    const __hip_bfloat16* __restrict__ A, int lda,
    const __hip_bfloat16* __restrict__ Bt,
    TC* __restrict__ C0, int ldc0, int sp0, int off0,
    TC* __restrict__ C1, int ldc1, int sp1, int off1,
    int splitN, int K)
{
    __shared__ alignas(16) __hip_bfloat16 As[128 * 32];
    __shared__ alignas(16) __hip_bfloat16 Bs[128 * 32];

    const int bn = blockIdx.x * 128;
    const int bm = blockIdx.y * 128;
    const int t = threadIdx.x;
    const int w = t >> 6;
    const int lane = t & 63;
    const int l15 = lane & 15;
    const int quad = lane >> 4;
    const int wm = (w & 1) * 64;
    const int wn = (w >> 1) * 64;

    const int srow = lane >> 2;          // 0..15
    const int skcol = (lane & 3) * 8;    // 0,8,16,24

    f32x4 acc[4][4] = {};

    for (int k0 = 0; k0 < K; k0 += 32) {
        __syncthreads();
        #pragma unroll
        for (int i = 0; i < 2; i++) {
            int r = w * 32 + i * 16 + srow;
            GLD16(A + (size_t)(bm + r) * lda + k0 + skcol, &As[r * 32 + skcol]);
            GLD16(Bt + (size_t)(bn + r) * K + k0 + skcol, &Bs[r * 32 + skcol]);
        }
        __syncthreads();

        bf16x8 af[4], bf[4];
        #pragma unroll
        for (int mt = 0; mt < 4; mt++)
            af[mt] = ld_frag(&As[(wm + mt * 16 + l15) * 32 + quad * 8]);
        #pragma unroll
        for (int nt = 0; nt < 4; nt++)
            bf[nt] = ld_frag(&Bs[(wn + nt * 16 + l15) * 32 + quad * 8]);
        #pragma unroll
        for (int mt = 0; mt < 4; mt++)
            #pragma unroll
            for (int nt = 0; nt < 4; nt++)
                acc[mt][nt] = __builtin_amdgcn_mfma_f32_16x16x32_bf16(
                    af[mt], bf[nt], acc[mt][nt], 0, 0, 0);
    }

    #pragma unroll
    for (int nt = 0; nt < 4; nt++) {
        int col = bn + wn + nt * 16 + l15;
        TC* Cp; int c, ld, s64, off;
        if (col < splitN) { Cp = C0; c = col; ld = ldc0; s64 = sp0; off = off0; }
        else { Cp = C1; c = col - splitN; ld = ldc1; s64 = sp1; off = off1; }
        if (s64 == 2) {
            // transposed: Cp[c][row], rows contiguous per quad (4 elems)
            #pragma unroll
            for (int mt = 0; mt < 4; mt++) {
                int row0 = bm + wm + mt * 16 + quad * 4;
                #pragma unroll
                for (int r = 0; r < 4; r++)
                    store_c(Cp, (size_t)c * 4096 + row0 + r, acc[mt][nt][r]);
            }
        } else {
            int oc = s64 ? ((c >> 6) * 128 + (c & 63) + off) : c;
            #pragma unroll
            for (int mt = 0; mt < 4; mt++) {
                #pragma unroll
                for (int r = 0; r < 4; r++) {
                    int row = bm + wm + mt * 16 + quad * 4 + r;
                    store_c(Cp, (size_t)row * ld + oc, acc[mt][nt][r]);
                }
            }
        }
    }
}

// ---------------------------------------------------------------------------
// RoPE in-place on K/Q rope halves: cols h*128+64+i and h*128+96+i rotated.
// ---------------------------------------------------------------------------
__global__ __launch_bounds__(256) void rope_kernel(
    __hip_bfloat16* __restrict__ Kb, __hip_bfloat16* __restrict__ Qb)
{
    int idx = blockIdx.x * blockDim.x + threadIdx.x;
    if (idx >= BS * NH * 32) return;
    int i = idx & 31;
    int h = (idx >> 5) & 15;
    int row = idx >> 9;
    int s = row & (SS - 1);

    float inv = exp2f(-(float)i * 0.4152410118609203f);  // 10000^(-i/32)
    float ang = (float)s * inv;
    float sn = sinf(ang), cs = cosf(ang);

    size_t obase = (size_t)row * 2048 + h * 128 + 64 + i;
    {
        float x1 = __bfloat162float(Kb[obase]);
        float x2 = __bfloat162float(Kb[obase + 32]);
        Kb[obase]      = __float2bfloat16(x1 * cs - x2 * sn);
        Kb[obase + 32] = __float2bfloat16(x1 * sn + x2 * cs);
    }
    {
        float x1 = __bfloat162float(Qb[obase]);
        float x2 = __bfloat162float(Qb[obase + 32]);
        Qb[obase]      = __float2bfloat16(x1 * cs - x2 * sn);
        Qb[obase + 32] = __float2bfloat16(x1 * sn + x2 * cs);
    }
}

// ---------------------------------------------------------------------------
// Flash attention v4. Block = 256 thr (4 waves), q-tile 128 (32 q/wave),
// kv-tile 64. K and Vt staged via global_load_lds (coalesced, m97 subtile
// layout + 16B-chunk XOR swizzle). S^T = K*Q^T per qsub; per-lane softmax
// (q = l15) with 2 shuffles; P -> Sp LDS -> A-frag; PV from Vt subtiles.
// V is pre-transposed globally: Vt[h*128+d][b*S+s].
// ---------------------------------------------------------------------------
__global__ __launch_bounds__(256) void flash_attn_kernel(
    const __hip_bfloat16* __restrict__ Q,
    const __hip_bfloat16* __restrict__ Kb,
    const __hip_bfloat16* __restrict__ Vt,
    __hip_bfloat16* __restrict__ O)
{
    __shared__ alignas(16) __hip_bfloat16 Kt[4 * 64 * 32];   // subtile ds: [64 kv][32 d]
    __shared__ alignas(16) __hip_bfloat16 Vs[2 * 128 * 32];  // subtile kvh: [128 d][32 kv]
    __shared__ alignas(16) __hip_bfloat16 Sp[4][32 * 72];    // per-wave P [32 q][72]

    const int bxq = (gridDim.x - 1) - blockIdx.x;   // big blocks first
    const int h = blockIdx.y;
    const int b = blockIdx.z;
    const int t = threadIdx.x;
    const int w = t >> 6;
    const int lane = t & 63;
    const int l15 = lane & 15;
    const int quad = lane >> 4;
    const int qbase = bxq * 128;

    const __hip_bfloat16* Kbase = Kb + (size_t)(b * SS) * 2048 + h * 128;
    const __hip_bfloat16* Vtb = Vt + (size_t)(h * 128) * 4096 + b * SS;

    // Q B-frags: qf[qs][ds], n = q = l15
    bf16x8 qf[2][4];
    #pragma unroll
    for (int qs = 0; qs < 2; qs++) {
        const __hip_bfloat16* qrow =
            Q + (size_t)(b * SS + qbase + w * 32 + qs * 16 + l15) * 2048 + h * 128;
        #pragma unroll
        for (int ds = 0; ds < 4; ds++)
            qf[qs][ds] = ld_frag(qrow + ds * 32 + quad * 8);
    }

    float m_i[2] = { -INFINITY, -INFINITY };
    float l_i[2] = { 0.0f, 0.0f };
    f32x4 acc[2][8] = {};

    const int Lr = lane >> 2;                 // 0..15 (row within issue)
    const int Lc = (lane & 3) ^ (Lr & 3);     // swizzled 16B chunk index
    const int kvh_w = w >> 1, dh_w = w & 1;   // V staging assignment
    const int ntiles = 2 * bxq + 2;

    for (int kt = 0; kt < ntiles; kt++) {
        const int kvbase = kt * 64;
        __syncthreads();   // all waves done reading prev tile's LDS

        // ---- stage K: wave w -> d-subtile w (4 issues x 1KB) ----
        #pragma unroll
        for (int i = 0; i < 4; i++) {
            GLD16(Kbase + (size_t)(kvbase + i * 16 + Lr) * 2048 + w * 32 + Lc * 8,
                  &Kt[w * 2048 + i * 512 + lane * 8]);
        }
        // ---- stage V: wave w -> kv-subtile w>>1, d-half w&1 ----
        #pragma unroll
        for (int i = 0; i < 4; i++) {
            GLD16(Vtb + (size_t)(dh_w * 64 + i * 16 + Lr) * 4096
                      + kvbase + kvh_w * 32 + Lc * 8,
                  &Vs[kvh_w * 4096 + dh_w * 2048 + i * 512 + lane * 8]);
        }
        __syncthreads();   // staged data visible

        // ---- S^T = K * Q^T ----
        f32x4 st[4][2];
        #pragma unroll
        for (int kvsub = 0; kvsub < 4; kvsub++) {
            st[kvsub][0] = f32x4{};
            st[kvsub][1] = f32x4{};
            #pragma unroll
            for (int ds = 0; ds < 4; ds++) {
                bf16x8 kf = ld_frag(&Kt[ds * 2048 + (kvsub * 16 + l15) * 32
                                        + (quad ^ (l15 & 3)) * 8]);
                #pragma unroll
                for (int qs = 0; qs < 2; qs++)
                    st[kvsub][qs] = __builtin_amdgcn_mfma_f32_16x16x32_bf16(
                        kf, qf[qs][ds], st[kvsub][qs], 0, 0, 0);
            }
        }
        // scale + causal mask
        #pragma unroll
        for (int qs = 0; qs < 2; qs++) {
            int q = qbase + w * 32 + qs * 16 + l15;
            #pragma unroll
            for (int kvsub = 0; kvsub < 4; kvsub++) {
                #pragma unroll
                for (int r = 0; r < 4; r++) {
                    int kv = kvbase + kvsub * 16 + quad * 4 + r;
                    st[kvsub][qs][r] = (kv <= q) ? st[kvsub][qs][r] * SCALE
                                                 : -INFINITY;
                }
            }
        }

        // ---- online softmax per qsub (q = l15, in-lane 16 + 2 shuffles) ----
        float alpha[2];
        #pragma unroll
        for (int qs = 0; qs < 2; qs++) {
            float tm = st[0][qs][0];
            #pragma unroll
            for (int kvsub = 0; kvsub < 4; kvsub++)
                #pragma unroll
                for (int r = 0; r < 4; r++) tm = fmaxf(tm, st[kvsub][qs][r]);
            tm = fmaxf(tm, __shfl_xor(tm, 16));
            tm = fmaxf(tm, __shfl_xor(tm, 32));
            float mnew = fmaxf(m_i[qs], tm);
            float rs = 0.0f;
            #pragma unroll
            for (int kvsub = 0; kvsub < 4; kvsub++)
                #pragma unroll
                for (int r = 0; r < 4; r++) {
                    float pv = __expf(st[kvsub][qs][r] - mnew);
                    st[kvsub][qs][r] = pv;
                    rs += pv;
                }
            rs += __shfl_xor(rs, 16);
            rs += __shfl_xor(rs, 32);
            alpha[qs] = __expf(m_i[qs] - mnew);
            m_i[qs] = mnew;
            l_i[qs] = l_i[qs] * alpha[qs] + rs;
        }

        // ---- write P to Sp (4 consecutive kv per b64 store) ----
        #pragma unroll
        for (int qs = 0; qs < 2; qs++) {
            #pragma unroll
            for (int kvsub = 0; kvsub < 4; kvsub++) {
                ushort pk[4] = { bf_bits(st[kvsub][qs][0]), bf_bits(st[kvsub][qs][1]),
                                 bf_bits(st[kvsub][qs][2]), bf_bits(st[kvsub][qs][3]) };
                *reinterpret_cast<uint2*>(
                    &Sp[w][(qs * 16 + l15) * 72 + kvsub * 16 + quad * 4]) =
                    *reinterpret_cast<uint2*>(pk);
            }
        }

        // ---- rescale O accumulator ----
        #pragma unroll
        for (int qs = 0; qs < 2; qs++) {
            float al[4];
            #pragma unroll
            for (int r = 0; r < 4; r++) al[r] = __shfl(alpha[qs], quad * 4 + r, 64);
            #pragma unroll
            for (int dt = 0; dt < 8; dt++)
                #pragma unroll
                for (int r = 0; r < 4; r++) acc[qs][dt][r] *= al[r];
        }

        // ---- PV: A = P (Sp, own wave's writes), B = V (Vs) ----
        #pragma unroll
        for (int kvh = 0; kvh < 2; kvh++) {
            bf16x8 pf[2];
            #pragma unroll
            for (int qs = 0; qs < 2; qs++)
                pf[qs] = ld_frag(&Sp[w][(qs * 16 + l15) * 72 + kvh * 32 + quad * 8]);
            #pragma unroll
            for (int dt = 0; dt < 8; dt++) {
                bf16x8 vf = ld_frag(&Vs[kvh * 4096 + (dt * 16 + l15) * 32
                                        + (quad ^ (l15 & 3)) * 8]);
                #pragma unroll
                for (int qs = 0; qs < 2; qs++)
                    acc[qs][dt] = __builtin_amdgcn_mfma_f32_16x16x32_bf16(
                        pf[qs], vf, acc[qs][dt], 0, 0, 0);
            }
        }
    }

    // ---- epilogue ----
    #pragma unroll
    for (int qs = 0; qs < 2; qs++) {
        float li[4];
        #pragma unroll
        for (int r = 0; r < 4; r++) li[r] = __shfl(l_i[qs], quad * 4 + r, 64);
        #pragma unroll
        for (int r = 0; r < 4; r++) {
            int row = qbase + w * 32 + qs * 16 + quad * 4 + r;
            __hip_bfloat16* orow = O + (size_t)(b * SS + row) * 2048 + h * 128;
            float inv_l = 1.0f / li[r];
            #pragma unroll
            for (int dt = 0; dt < 8; dt++)
                orow[dt * 16 + l15] = __float2bfloat16(acc[qs][dt][r] * inv_l);
        }
    }
}

// ---------------------------------------------------------------------------
extern "C" void kernel_launch(void* const* d_in, const int* in_sizes, int n_in,
                              void* d_out, int out_size, void* d_ws, size_t ws_size,
                              hipStream_t stream)
{
    const float* hs       = (const float*)d_in[0];
    const float* w_kv_d   = (const float*)d_in[1];
    const float* w_q_d    = (const float*)d_in[2];
    const float* w_k_u    = (const float*)d_in[3];
    const float* w_q_u    = (const float*)d_in[4];
    const float* w_v_u    = (const float*)d_in[5];
    const float* w_rope_k = (const float*)d_in[6];
    const float* w_rope_q = (const float*)d_in[7];
    const float* w_o      = (const float*)d_in[8];
    float* out = (float*)d_out;

    char* p = (char*)d_ws;
    auto alloc = [&](size_t nelem) {
        __hip_bfloat16* r = (__hip_bfloat16*)p;
        p += nelem * sizeof(__hip_bfloat16);
        return r;
    };
    __hip_bfloat16* hsb  = alloc((size_t)BS * HID);        // 16 MB (reused as attn)
    __hip_bfloat16* qkvd = alloc((size_t)BS * 512);        // 4 MB
    __hip_bfloat16* WT1  = alloc((size_t)1536 * 2048);     // 6 MB
    __hip_bfloat16* WT2  = alloc((size_t)3072 * 256);      // 1.5 MB
    __hip_bfloat16* WT3  = alloc((size_t)2048 * 256);      // 1 MB
    __hip_bfloat16* WTo  = alloc((size_t)2048 * 2048);     // 8 MB
    __hip_bfloat16* Kbuf = alloc((size_t)BS * HID);        // 16 MB
    __hip_bfloat16* Qbuf = alloc((size_t)BS * HID);        // 16 MB
    __hip_bfloat16* Vtb  = alloc((size_t)HID * BS);        // 16 MB, [h*128+d][b*S+s]
    __hip_bfloat16* attn = hsb;   // hs dead after G1

    dim3 blk(256);

    // 0a. hs -> bf16
    convert_kernel<<<dim3((BS * HID / 8 + 255) / 256), blk, 0, stream>>>(
        hs, hsb, BS * HID / 8);
    // 0b. all weights: transpose + convert to bf16 W^T
    transpose_weights_kernel<<<dim3(8448), blk, 0, stream>>>(
        w_kv_d, w_q_d, w_rope_k, w_k_u, w_v_u, w_q_u, w_rope_q, w_o,
        WT1, WT2, WT3, WTo);

    // G1: [kv_d | q_d | krp] = hsb @ WT1^T  (N=1536, K=2048)
    gemm_bt_kernel<__hip_bfloat16><<<dim3(1536 / 128, BS / 128), blk, 0, stream>>>(
        hsb, 2048, WT1,
        qkvd, 512, 0, 0,
        Kbuf, 2048, 1, 64,
        512, 2048);
    // G2: [k_p | v] = kv_d @ WT2^T  (N=3072, K=256)
    //     cols 0..1023 -> Kbuf nope half (split64); 1024..3071 -> Vt transposed
    gemm_bt_kernel<__hip_bfloat16><<<dim3(3072 / 128, BS / 128), blk, 0, stream>>>(
        qkvd, 512, WT2,
        Kbuf, 2048, 1, 0,
        Vtb, 0, 2, 0,
        1024, 256);
    // G3: [q_p | q_rope_pre] = q_d @ WT3^T  (N=2048, K=256)
    gemm_bt_kernel<__hip_bfloat16><<<dim3(2048 / 128, BS / 128), blk, 0, stream>>>(
        qkvd + 256, 512, WT3,
        Qbuf, 2048, 1, 0,
        Qbuf, 2048, 1, 64,
        1024, 256);
    // 4. RoPE in-place on K/Q rope halves
    rope_kernel<<<dim3((BS * NH * 32 + 255) / 256), blk, 0, stream>>>(Kbuf, Qbuf);
    // 5. flash attention v4 -> attn
    flash_attn_kernel<<<dim3(SS / 128, NH, BB), blk, 0, stream>>>(
        Qbuf, Kbuf, Vtb, attn);
    // G4: out = attn @ WTo^T (fp32 out)
    gemm_bt_kernel<float><<<dim3(2048 / 128, BS / 128), blk, 0, stream>>>(
        attn, 2048, WTo,
        out, 2048, 0, 0,
        out, 2048, 0, 0,
        2048, 2048);
}